// Round 2
// baseline (757.020 us; speedup 1.0000x reference)
//
#include <hip/hip_runtime.h>

#define TT   512
#define BATCH 2048
#define DIN  64
#define HD   10

// One wave (64 threads) per batch row. Lanes 0..39 = (gate, q) pairs:
// gate g = lane/10 in {f,i,u,o}, hidden index q = lane%10. Lanes 40..63 idle
// (kept NaN-free with zeroed weights). All cross-lane traffic stays in-wave
// (shuffles/readlane) -> zero barriers across the 512-step loop.
__global__ __launch_bounds__(64, 2)
void qlstm_kernel(const float* __restrict__ X,
                  const float* __restrict__ Wf, const float* __restrict__ bf,
                  const float* __restrict__ Wi, const float* __restrict__ bi,
                  const float* __restrict__ Wu, const float* __restrict__ bu,
                  const float* __restrict__ Wo, const float* __restrict__ bo,
                  float* __restrict__ out)
{
    const int row  = blockIdx.x;
    const int lane = threadIdx.x;
    const int g    = lane / HD;        // gate id (garbage for lane>=40)
    const int q    = lane - g * HD;    // hidden index within gate
    const int gb   = g * HD;           // gate group base lane

    __shared__ float xs[2][DIN];       // double-buffered broadcast row of x

    const float LOG2E = 1.4426950408889634f;
    const float INV2PI = 0.15915494309189535f;

    // Per-lane weight row (W[q, 0:64] for x, W[q, 64:74] for h) + bias.
    float wx[DIN];
    float wh[HD];
    float bias = 0.f;
    // unified activation: a = amul * sigmoid-core + aadd
    float cmul = -LOG2E, amul = 1.f, aadd = 0.f;

    const float* Wg = Wf; const float* bg = bf;
    if (g == 1) { Wg = Wi; bg = bi; }
    else if (g == 2) { Wg = Wu; bg = bu; cmul = -2.f * LOG2E; amul = 2.f; aadd = -1.f; }
    else if (g == 3) { Wg = Wo; bg = bo; }

    if (lane < 4 * HD) {
        #pragma unroll
        for (int k = 0; k < DIN; ++k) wx[k] = Wg[q * (DIN + HD) + k];
        #pragma unroll
        for (int k = 0; k < HD; ++k)  wh[k] = Wg[q * (DIN + HD) + DIN + k];
        bias = bg[q];
    } else {
        #pragma unroll
        for (int k = 0; k < DIN; ++k) wx[k] = 0.f;
        #pragma unroll
        for (int k = 0; k < HD; ++k)  wh[k] = 0.f;
    }

    // replicated hidden state (uniform values -> SGPRs) and per-lane cell state
    float h[HD];
    #pragma unroll
    for (int k = 0; k < HD; ++k) h[k] = 0.f;
    float c = 0.f;
    float hlast = 0.f;

    const size_t xstep = (size_t)BATCH * DIN;

    // preload x row for t=0
    xs[0][lane] = X[(size_t)row * DIN + lane];

    int cur = 0;
    for (int t = 0; t < TT; ++t) {
        // prefetch next timestep's x row (coalesced vector load)
        float xn = 0.f;
        if (t + 1 < TT) xn = X[(size_t)(t + 1) * xstep + (size_t)row * DIN + lane];

        // z = bias + Wx . x  (x broadcast from LDS, 4 at a time) + Wh . h
        float z = bias;
        #pragma unroll
        for (int k4 = 0; k4 < DIN / 4; ++k4) {
            float4 xq = *reinterpret_cast<const float4*>(&xs[cur][k4 * 4]);
            z += wx[k4 * 4 + 0] * xq.x;
            z += wx[k4 * 4 + 1] * xq.y;
            z += wx[k4 * 4 + 2] * xq.z;
            z += wx[k4 * 4 + 3] * xq.w;
        }
        #pragma unroll
        for (int k = 0; k < HD; ++k) z += wh[k] * h[k];

        // clip and cos
        z = fminf(fmaxf(z, -5.f), 5.f);
        float p = __builtin_amdgcn_cosf(z * INV2PI);

        // inclusive prefix product across the 10-lane gate group
        #pragma unroll
        for (int off = 1; off < 16; off <<= 1) {
            float other = __shfl(p, lane - off);
            p = (q >= off) ? p * other : p;
        }
        // flip: gate value for q is cumprod at (9 - q)
        float G = __shfl(p, gb + (HD - 1) - q);

        // activation: sigmoid for f,i,o ; tanh for u (uniform formula, no branch)
        float e = __builtin_amdgcn_exp2f(cmul * G);
        float r = __builtin_amdgcn_rcpf(1.f + e);
        float a = amul * r + aadd;

        // gather the four gate values for this lane's q
        float fg = __shfl(a, q);
        float ig = __shfl(a, HD + q);
        float ug = __shfl(a, 2 * HD + q);
        float og = __shfl(a, 3 * HD + q);

        // cell + hidden update (replicated on all 4 gate groups)
        c = fg * c + ig * ug;
        float e2 = __builtin_amdgcn_exp2f(-2.f * LOG2E * c);
        float th = 2.f * __builtin_amdgcn_rcpf(1.f + e2) - 1.f;   // tanh(c)
        float hpre = og * th;
        float h9 = __int_as_float(__builtin_amdgcn_readlane(__float_as_int(hpre), 9));
        float m = __builtin_amdgcn_cosf(h9 * INV2PI);
        float hnew = hpre * m;
        hlast = hnew;

        // replicate new hidden state (uniform -> SGPR) for next step's dot
        #pragma unroll
        for (int k = 0; k < HD; ++k)
            h[k] = __int_as_float(__builtin_amdgcn_readlane(__float_as_int(hnew), k));

        // store outputs[t, row, q] (lanes 0..9 carry q = lane)
        if (lane < HD) out[((size_t)t * BATCH + row) * HD + lane] = hnew;

        // stage next x row into the other LDS slot (same wave -> no barrier)
        int nxt = cur ^ 1;
        if (t + 1 < TT) xs[nxt][lane] = xn;
        cur = nxt;
    }

    // final (hx, cx)
    if (lane < HD) {
        size_t base = (size_t)TT * BATCH * HD;
        out[base + (size_t)row * HD + lane] = hlast;               // hx
        out[base + (size_t)BATCH * HD + (size_t)row * HD + lane] = c; // cx
    }
}

extern "C" void kernel_launch(void* const* d_in, const int* in_sizes, int n_in,
                              void* d_out, int out_size, void* d_ws, size_t ws_size,
                              hipStream_t stream) {
    const float* X  = (const float*)d_in[0];
    const float* Wf = (const float*)d_in[1];
    const float* bf = (const float*)d_in[2];
    const float* Wi = (const float*)d_in[3];
    const float* bi = (const float*)d_in[4];
    const float* Wu = (const float*)d_in[5];
    const float* bu = (const float*)d_in[6];
    const float* Wo = (const float*)d_in[7];
    const float* bo = (const float*)d_in[8];
    float* out = (float*)d_out;

    qlstm_kernel<<<BATCH, 64, 0, stream>>>(X, Wf, bf, Wi, bi, Wu, bu, Wo, bo, out);
}

// Round 3
// 638.506 us; speedup vs baseline: 1.1856x; 1.1856x over previous
//
#include <hip/hip_runtime.h>

#define TT    512
#define BATCH 2048
#define DIN   64
#define HD    10
#define WROW  (DIN + HD)   // 74

// One wave per batch row. Lane = 16*g + v: g = gate {f,i,u,o}, v = within-row pos.
//  - weight role (v in [6,15]): owns unit uw = 15 - v  (reversed so the
//    flip(cumprod) of the quantum gate becomes a row_shl suffix product)
//  - state  role (v in [6,15]): owns unit us = v - 6 (scan result lands here)
// Lanes v<6 are dummies (zero weights -> z=0 -> cos=1, harmless to the scan).
// Cross-lane per step: 4 serial DPP (VALU) + 4 parallel bpermute + readlanes.
// zx[t+1] (x-dot) is computed one step ahead, off the recurrence chain.
__global__ __launch_bounds__(64, 2)
void qlstm_kernel(const float* __restrict__ X,
                  const float* __restrict__ Wf, const float* __restrict__ bf,
                  const float* __restrict__ Wi, const float* __restrict__ bi,
                  const float* __restrict__ Wu, const float* __restrict__ bu,
                  const float* __restrict__ Wo, const float* __restrict__ bo,
                  float* __restrict__ out)
{
    const int row  = blockIdx.x;
    const int lane = threadIdx.x;
    const int g    = lane >> 4;
    const int v    = lane & 15;
    const bool act_lane = (v >= 6);

    __shared__ float xs[2][DIN];

    const float LOG2E  = 1.4426950408889634f;
    const float INV2PI = 0.15915494309189535f;

    // unified activation: a = amul * rcp(1 + exp2(cmul*G)) + aadd
    float cmul = -LOG2E, amul = 1.f, aadd = 0.f;
    const float* Wg = Wf; const float* bg = bf;
    if (g == 1) { Wg = Wi; bg = bi; }
    else if (g == 2) { Wg = Wu; bg = bu; cmul = -2.f * LOG2E; amul = 2.f; aadd = -1.f; }
    else if (g == 3) { Wg = Wo; bg = bo; }

    float wx[DIN];
    float wh[HD];
    float bias = 0.f;
    if (act_lane) {
        const int uw = 15 - v;                 // unit owned for the z/cos computation
        #pragma unroll
        for (int k = 0; k < DIN; ++k) wx[k] = Wg[uw * WROW + k];
        #pragma unroll
        for (int k = 0; k < HD; ++k)  wh[k] = Wg[uw * WROW + DIN + k];
        bias = bg[uw];
    } else {
        #pragma unroll
        for (int k = 0; k < DIN; ++k) wx[k] = 0.f;
        #pragma unroll
        for (int k = 0; k < HD; ++k)  wh[k] = 0.f;
    }

    float h[HD];                                // uniform (SGPR) replicated hidden state
    #pragma unroll
    for (int k = 0; k < HD; ++k) h[k] = 0.f;
    float c = 0.f;
    float hkeep = 0.f;

    const size_t xstep = (size_t)BATCH * DIN;
    const size_t xbase = (size_t)row * DIN + lane;

    // prologue: x[0] -> LDS slot 0, zx for t=0, prefetch x[1] into regs
    xs[0][lane] = X[xbase];
    float xr = X[xstep + xbase];                // x[1] (TT > 1 always)

    float zx;
    {
        float s0 = bias, s1 = 0.f, s2 = 0.f, s3 = 0.f;
        #pragma unroll
        for (int k = 0; k < DIN; k += 4) {
            float4 xq = *reinterpret_cast<const float4*>(&xs[0][k]);
            s0 = fmaf(wx[k + 0], xq.x, s0);
            s1 = fmaf(wx[k + 1], xq.y, s1);
            s2 = fmaf(wx[k + 2], xq.z, s2);
            s3 = fmaf(wx[k + 3], xq.w, s3);
        }
        zx = (s0 + s1) + (s2 + s3);
    }

    int cur = 0;
    for (int t = 0; t < TT; ++t) {
        const int nxt = cur ^ 1;
        // stage x[t+1] into LDS, prefetch x[t+2]
        if (t + 1 < TT) xs[nxt][lane] = xr;
        if (t + 2 < TT) xr = X[(size_t)(t + 2) * xstep + xbase];

        // ---------- recurrence chain for step t ----------
        float za = zx, zb = 0.f;
        #pragma unroll
        for (int j = 0; j < HD; j += 2) {
            za = fmaf(wh[j],     h[j],     za);
            zb = fmaf(wh[j + 1], h[j + 1], zb);
        }
        float z = za + zb;
        z = fminf(fmaxf(z, -5.f), 5.f);
        float p = __builtin_amdgcn_cosf(z * INV2PI);

        // suffix product within each 16-lane row: p[v] = prod_{v'>=v} p[v']
        // row_shl:N -> dest[i] = src[i+N]; OOB lanes keep old (=1.0)
        {
            int s_;
            s_ = __builtin_amdgcn_update_dpp(0x3f800000, __float_as_int(p), 0x101, 0xF, 0xF, false);
            p *= __int_as_float(s_);
            s_ = __builtin_amdgcn_update_dpp(0x3f800000, __float_as_int(p), 0x102, 0xF, 0xF, false);
            p *= __int_as_float(s_);
            s_ = __builtin_amdgcn_update_dpp(0x3f800000, __float_as_int(p), 0x104, 0xF, 0xF, false);
            p *= __int_as_float(s_);
            s_ = __builtin_amdgcn_update_dpp(0x3f800000, __float_as_int(p), 0x108, 0xF, 0xF, false);
            p *= __int_as_float(s_);
        }
        // p at lane v is now G for unit (v-6)

        float e = __builtin_amdgcn_exp2f(cmul * p);
        float a = amul * __builtin_amdgcn_rcpf(1.f + e) + aadd;

        // gather the 4 gate values for this lane's unit (same v across groups)
        float fg = __shfl(a, v);
        float ig = __shfl(a, 16 + v);
        float ug = __shfl(a, 32 + v);
        float og = __shfl(a, 48 + v);

        c = fmaf(fg, c, ig * ug);
        float e2 = __builtin_amdgcn_exp2f(-2.f * LOG2E * c);
        float th = 2.f * __builtin_amdgcn_rcpf(1.f + e2) - 1.f;   // tanh(c)
        float hpre = og * th;
        float h9 = __int_as_float(__builtin_amdgcn_readlane(__float_as_int(hpre), 15)); // unit 9
        float m  = __builtin_amdgcn_cosf(h9 * INV2PI);
        float hnew = hpre * m;
        hkeep = hnew;

        // store outputs[t, row, us] from group-0 state lanes (lanes 6..15)
        if (lane >= 6 && lane < 16) out[((size_t)t * BATCH + row) * HD + (lane - 6)] = hnew;

        // replicate h (uniform -> SGPR) for next step's h-dot
        #pragma unroll
        for (int j = 0; j < HD; ++j)
            h[j] = __int_as_float(__builtin_amdgcn_readlane(__float_as_int(hnew), 6 + j));

        // ---------- zx for step t+1 (independent of the chain) ----------
        if (t + 1 < TT) {
            float s0 = bias, s1 = 0.f, s2 = 0.f, s3 = 0.f;
            const float* xp = xs[nxt];
            #pragma unroll
            for (int k = 0; k < DIN; k += 4) {
                float4 xq = *reinterpret_cast<const float4*>(&xp[k]);
                s0 = fmaf(wx[k + 0], xq.x, s0);
                s1 = fmaf(wx[k + 1], xq.y, s1);
                s2 = fmaf(wx[k + 2], xq.z, s2);
                s3 = fmaf(wx[k + 3], xq.w, s3);
            }
            zx = (s0 + s1) + (s2 + s3);
        }
        cur = nxt;
    }

    // final (hx, cx) from group-0 state lanes
    if (lane >= 6 && lane < 16) {
        const size_t base = (size_t)TT * BATCH * HD;
        out[base + (size_t)row * HD + (lane - 6)] = hkeep;
        out[base + (size_t)BATCH * HD + (size_t)row * HD + (lane - 6)] = c;
    }
}

extern "C" void kernel_launch(void* const* d_in, const int* in_sizes, int n_in,
                              void* d_out, int out_size, void* d_ws, size_t ws_size,
                              hipStream_t stream) {
    const float* X  = (const float*)d_in[0];
    const float* Wf = (const float*)d_in[1];
    const float* bf = (const float*)d_in[2];
    const float* Wi = (const float*)d_in[3];
    const float* bi = (const float*)d_in[4];
    const float* Wu = (const float*)d_in[5];
    const float* bu = (const float*)d_in[6];
    const float* Wo = (const float*)d_in[7];
    const float* bo = (const float*)d_in[8];
    float* out = (float*)d_out;

    qlstm_kernel<<<BATCH, 64, 0, stream>>>(X, Wf, bf, Wi, bi, Wu, bu, Wo, bo, out);
}